// Round 3
// baseline (159.692 us; speedup 1.0000x reference)
//
#include <hip/hip_runtime.h>
#include <cstdint>
#include <cstddef>

// ---------------------------------------------------------------------------
// RNN_No_FFNN: h_t = sigmoid(hidden@U_w.T + U_b + line@W_w.T + W_b)
//              pred = h_t@V_w.T + V_b ; out0 = segmented log_softmax(pred)
// B=8192, H=2048, D=104.  Outputs: [pred_logsoft (8192*104) | h_t (8192*2048)] f32.
// gemm1 (R3): m97-style 128x128 tile, BK=64, SINGLE-buffered 32KB LDS ->
//   ~4 blocks/CU co-resident (cross-block overlap = the m97 engine),
//   __syncthreads-managed waits, XOR slot swizzle (conflict-free),
//   global_load_lds w16 staging with 128B row segments.
// ---------------------------------------------------------------------------

typedef __bf16 bf16x8 __attribute__((ext_vector_type(8)));
typedef float  f32x4  __attribute__((ext_vector_type(4)));
typedef unsigned short ushort8 __attribute__((ext_vector_type(8)));
typedef float  float4v __attribute__((ext_vector_type(4)));

#define BB 8192
#define HH 2048
#define DD 104

static __device__ __forceinline__ unsigned short f2bf(float f) {
  unsigned u = __float_as_uint(f);
  unsigned r = (u + 0x7FFFu + ((u >> 16) & 1u)) >> 16;  // RNE
  return (unsigned short)r;
}

// async global->LDS, 16B per lane
#define GLD_LDS(g, l)                                                          \
  __builtin_amdgcn_global_load_lds(                                            \
      (__attribute__((address_space(1))) void*)(g),                            \
      (__attribute__((address_space(3))) void*)(l), 16, 0, 0)

// ---------------------------------------------------------------------------
// Conversion kernels (unchanged)
// ---------------------------------------------------------------------------
__global__ __launch_bounds__(256) void conv_bf16_kernel(
    const float* __restrict__ hidden, const float* __restrict__ Uw,
    unsigned short* __restrict__ out_hidden, unsigned short* __restrict__ out_U) {
  long long i = ((long long)blockIdx.x * blockDim.x + threadIdx.x) * 8;
  const float* src; unsigned short* dst; long long off;
  if (i < (long long)BB * HH) { src = hidden; dst = out_hidden; off = i; }
  else { src = Uw; dst = out_U; off = i - (long long)BB * HH; }
  float4v a = *(const float4v*)(src + off);
  float4v b = *(const float4v*)(src + off + 4);
  ushort8 o;
  o[0]=f2bf(a[0]); o[1]=f2bf(a[1]); o[2]=f2bf(a[2]); o[3]=f2bf(a[3]);
  o[4]=f2bf(b[0]); o[5]=f2bf(b[1]); o[6]=f2bf(b[2]); o[7]=f2bf(b[3]);
  *(ushort8*)(dst + off) = o;
}

__global__ __launch_bounds__(256) void pad_bf16_kernel(
    const float* __restrict__ line, const float* __restrict__ Ww,
    const float* __restrict__ Vw,
    unsigned short* __restrict__ line_pad, unsigned short* __restrict__ Ww_pad,
    unsigned short* __restrict__ Vw_pad) {
  int i = blockIdx.x * blockDim.x + threadIdx.x;
  const int N1 = BB * 128;          // 1048576
  const int N2 = N1 + HH * 128;     // +262144
  if (i < N1) {
    int r = i >> 7, c = i & 127;
    line_pad[i] = (c < DD) ? f2bf(line[r * DD + c]) : (unsigned short)0;
  } else if (i < N2) {
    int j = i - N1; int r = j >> 7, c = j & 127;
    Ww_pad[j] = (c < DD) ? f2bf(Ww[r * DD + c]) : (unsigned short)0;
  } else {
    int j = i - N2; int r = j >> 11, c = j & 2047;
    Vw_pad[j] = (r < DD) ? f2bf(Vw[r * 2048 + c]) : (unsigned short)0;
  }
}

// ---------------------------------------------------------------------------
// BK=64 MFMA step with XOR slot swizzle.
// LDS tile [rows][64] bf16; LDS[row][slot] = global[row][slot ^ (row&7)]
// (slot = 8-element group). Read: slot_r = (ks*4 + (l>>4)) ^ (frow&7).
// ---------------------------------------------------------------------------
template <int NM, int NN>
static __device__ __forceinline__ void mfma_bk64(
    const unsigned short* sA, const unsigned short* sB, int arow0, int brow0,
    int frow, int lhi, f32x4 (&acc)[NM][NN]) {
  const int fx = frow & 7;
#pragma unroll
  for (int ks = 0; ks < 2; ++ks) {
    bf16x8 af[NM], bfr[NN];
    const int sbase = ks * 4 + lhi;
#pragma unroll
    for (int m = 0; m < NM; ++m) {
      const int r = arow0 + m * 16 + frow;
      af[m] = *(const bf16x8*)(sA + r * 64 + ((sbase ^ fx) * 8));
    }
#pragma unroll
    for (int n = 0; n < NN; ++n) {
      const int r = brow0 + n * 16 + frow;
      bfr[n] = *(const bf16x8*)(sB + r * 64 + ((sbase ^ fx) * 8));
    }
#pragma unroll
    for (int m = 0; m < NM; ++m)
#pragma unroll
      for (int n = 0; n < NN; ++n)
        acc[m][n] = __builtin_amdgcn_mfma_f32_16x16x32_bf16(af[m], bfr[n], acc[m][n], 0, 0, 0);
  }
}

// ---------------------------------------------------------------------------
// GEMM1: 128x128 tile, BK=64, single-buffer, 256 threads (2x2 waves, 64x64/wave)
// K = 2048 (hidden/U_w) then 128 (line_pad/Ww_pad) = 34 iters of 64.
// ---------------------------------------------------------------------------
__global__ __launch_bounds__(256) void gemm1_kernel(
    const unsigned short* __restrict__ Ahid,   // [8192][2048] bf16
    const unsigned short* __restrict__ Aline,  // [8192][128]  bf16 (zero-pad)
    const unsigned short* __restrict__ BU,     // [2048][2048] bf16
    const unsigned short* __restrict__ BW,     // [2048][128]  bf16 (zero-pad)
    const float* __restrict__ Ub, const float* __restrict__ Wb,
    float* __restrict__ outH, unsigned short* __restrict__ outHbf) {
  __shared__ unsigned short sA[128 * 64];   // 16 KB
  __shared__ unsigned short sB[128 * 64];   // 16 KB
  const int t = threadIdx.x;
  const int l = t & 63;
  const int wid = t >> 6, wr = wid >> 1, wc = wid & 1;

  // XCD-chunked bijective swizzle: 1024 wgs, 8 XCDs, 128/chunk
  const int bid = blockIdx.x;
  const int wg = (bid & 7) * 128 + (bid >> 3);
  const int brow = (wg >> 4) * 128;   // 64 M tiles
  const int bcol = (wg & 15) * 128;   // 16 N tiles

  const int frow = l & 15, lhi = l >> 4;

  // staging: thread t -> row t>>3 (+32 per GLD), source slot pre-swizzled
  const int srow = t >> 3;
  const int sslot = ((t & 7) ^ (srow & 7)) * 8;
  const unsigned short* gA1 = Ahid + (size_t)(brow + srow) * 2048 + sslot;
  const unsigned short* gB1 = BU + (size_t)(bcol + srow) * 2048 + sslot;
  const unsigned short* gA2 = Aline + (size_t)(brow + srow) * 128 + sslot;
  const unsigned short* gB2 = BW + (size_t)(bcol + srow) * 128 + sslot;
  unsigned short* dA = sA + t * 8;   // + p*2048 elems per GLD chunk (32 rows)
  unsigned short* dB = sB + t * 8;

  f32x4 acc[4][4] = {};

  // main K: 32 iters over hidden/U_w
  for (int it = 0; it < 32; ++it) {
    const int kb = it * 64;
    __syncthreads();
#pragma unroll
    for (int p = 0; p < 4; ++p) GLD_LDS(gA1 + kb + p * 32 * 2048, dA + p * 2048);
#pragma unroll
    for (int p = 0; p < 4; ++p) GLD_LDS(gB1 + kb + p * 32 * 2048, dB + p * 2048);
    __syncthreads();
    mfma_bk64<4, 4>(sA, sB, wr * 64, wc * 64, frow, lhi, acc);
  }
  // tail K: 2 iters over line_pad/Ww_pad (zero-padded cols 104..127)
  for (int it = 0; it < 2; ++it) {
    const int kb = it * 64;
    __syncthreads();
#pragma unroll
    for (int p = 0; p < 4; ++p) GLD_LDS(gA2 + kb + p * 32 * 128, dA + p * 2048);
#pragma unroll
    for (int p = 0; p < 4; ++p) GLD_LDS(gB2 + kb + p * 32 * 128, dB + p * 2048);
    __syncthreads();
    mfma_bk64<4, 4>(sA, sB, wr * 64, wc * 64, frow, lhi, acc);
  }

  // epilogue: +bias, sigmoid, dual write (C/D layout: col=l&15, row=(l>>4)*4+j)
#pragma unroll
  for (int n = 0; n < 4; ++n) {
    const int col = bcol + wc * 64 + n * 16 + frow;
    const float bias = Ub[col] + Wb[col];
#pragma unroll
    for (int m = 0; m < 4; ++m) {
      const int r0 = brow + wr * 64 + m * 16 + lhi * 4;
#pragma unroll
      for (int jj = 0; jj < 4; ++jj) {
        const float v = acc[m][n][jj] + bias;
        const float h = 1.0f / (1.0f + __expf(-v));
        const size_t idx = (size_t)(r0 + jj) * HH + col;
        outH[idx] = h;
        outHbf[idx] = f2bf(h);
      }
    }
  }
}

// ---------------------------------------------------------------------------
// GEMM2 (unchanged from R2): pred = h_t@V_w.T + V_b + fused seg log-softmax
// ---------------------------------------------------------------------------
template <int NM, int NN>
static __device__ __forceinline__ void mfma_step(
    const unsigned short* sA, const unsigned short* sB, int arow0, int brow0,
    int frow, int fk, f32x4 (&acc)[NM][NN]) {
  bf16x8 af[NM], bfr[NN];
#pragma unroll
  for (int m = 0; m < NM; ++m)
    af[m] = *(const bf16x8*)(sA + (arow0 + m * 16 + frow) * 32 + fk);
#pragma unroll
  for (int n = 0; n < NN; ++n)
    bfr[n] = *(const bf16x8*)(sB + (brow0 + n * 16 + frow) * 32 + fk);
#pragma unroll
  for (int m = 0; m < NM; ++m)
#pragma unroll
    for (int n = 0; n < NN; ++n)
      acc[m][n] = __builtin_amdgcn_mfma_f32_16x16x32_bf16(af[m], bfr[n], acc[m][n], 0, 0, 0);
}

__global__ __launch_bounds__(256, 2) void gemm2_kernel(
    const unsigned short* __restrict__ A,   // h_t bf16 [8192][2048]
    const unsigned short* __restrict__ Bm,  // Vw_pad [128][2048]
    const float* __restrict__ Vb,
    float* __restrict__ outLS) {            // [8192][104] f32
  __shared__ unsigned short sA[64 * 32];
  __shared__ unsigned short sB[128 * 32];
  __shared__ float pred[64 * 105];
  const int t = threadIdx.x;
  const int l = t & 63;
  const int wid = t >> 6, wr = wid >> 1, wc = wid & 1;
  const int brow = blockIdx.x * 64;
  const int srow = t >> 2, scg = t & 3;
  const int frow = l & 15, fk = (l >> 4) * 8;

  const unsigned short* gA = A + (size_t)(brow + srow) * HH + scg * 8;
  const unsigned short* gB = Bm + (size_t)srow * HH + scg * 8;
  unsigned short* lA = sA + t * 8;
  unsigned short* lB = sB + t * 8;

  f32x4 acc[2][4] = {};
  for (int ks = 0; ks < 64; ++ks) {
    __syncthreads();
    GLD_LDS(gA, lA);
    GLD_LDS(gB, lB);
    GLD_LDS(gB + 64 * HH, lB + 64 * 32);
    gA += 32; gB += 32;
    __syncthreads();
    mfma_step<2, 4>(sA, sB, wr * 32, wc * 64, frow, fk, acc);
  }

#pragma unroll
  for (int n = 0; n < 4; ++n) {
    const int col = wc * 64 + n * 16 + frow;
    if (col < DD) {
      const float vb = Vb[col];
#pragma unroll
      for (int m = 0; m < 2; ++m) {
        const int r0 = wr * 32 + m * 16 + (l >> 4) * 4;
#pragma unroll
        for (int j = 0; j < 4; ++j)
          pred[(r0 + j) * 105 + col] = acc[m][n][j] + vb;
      }
    }
  }
  __syncthreads();

  if (t < 64) {
    const int segb[11] = {0, 13, 26, 39, 48, 52, 65, 78, 91, 100, 104};
    const float* p = pred + t * 105;
    float* o = outLS + (size_t)(brow + t) * DD;
    for (int s = 0; s < 10; ++s) {
      const int a = segb[s], b = segb[s + 1];
      float mx = -3.0e38f;
      for (int c = a; c < b; ++c) mx = fmaxf(mx, p[c]);
      float sum = 0.0f;
      for (int c = a; c < b; ++c) sum += __expf(p[c] - mx);
      const float ls = __logf(sum) + mx;
      for (int c = a; c < b; ++c) o[c] = p[c] - ls;
    }
  }
}

// ---------------------------------------------------------------------------
// Launch
// ---------------------------------------------------------------------------
extern "C" void kernel_launch(void* const* d_in, const int* in_sizes, int n_in,
                              void* d_out, int out_size, void* d_ws, size_t ws_size,
                              hipStream_t stream) {
  (void)in_sizes; (void)n_in; (void)out_size; (void)ws_size;
  const float* line   = (const float*)d_in[0];
  const float* hidden = (const float*)d_in[1];
  const float* Uw     = (const float*)d_in[2];
  const float* Ub     = (const float*)d_in[3];
  const float* Ww     = (const float*)d_in[4];
  const float* Wb     = (const float*)d_in[5];
  const float* Vw     = (const float*)d_in[6];
  const float* Vb     = (const float*)d_in[7];

  char* ws = (char*)d_ws;
  unsigned short* hid_bf  = (unsigned short*)(ws);              // 33,554,432 B
  unsigned short* U_bf    = (unsigned short*)(ws + 33554432);   //  8,388,608
  unsigned short* line_bf = (unsigned short*)(ws + 41943040);   //  2,097,152
  unsigned short* Ww_bf   = (unsigned short*)(ws + 44040192);   //    524,288
  unsigned short* Vw_bf   = (unsigned short*)(ws + 44564480);   //    524,288
  unsigned short* ht_bf   = (unsigned short*)(ws + 45088768);   // 33,554,432

  float* outLS = (float*)d_out;                    // [8192][104]
  float* outH  = (float*)d_out + (size_t)BB * DD;  // [8192][2048]

  conv_bf16_kernel<<<10240, 256, 0, stream>>>(hidden, Uw, hid_bf, U_bf);
  pad_bf16_kernel<<<6144, 256, 0, stream>>>(line, Ww, Vw, line_bf, Ww_bf, Vw_bf);
  gemm1_kernel<<<1024, 256, 0, stream>>>(hid_bf, line_bf, U_bf, Ww_bf, Ub, Wb,
                                         outH, ht_bf);
  gemm2_kernel<<<128, 256, 0, stream>>>(ht_bf, Vw_bf, Vb, outLS);
}

// Round 4
// 158.057 us; speedup vs baseline: 1.0103x; 1.0103x over previous
//
#include <hip/hip_runtime.h>
#include <cstdint>
#include <cstddef>

// ---------------------------------------------------------------------------
// RNN_No_FFNN: h_t = sigmoid(hidden@U_w.T + U_b + line@W_w.T + W_b)
//              pred = h_t@V_w.T + V_b ; out0 = segmented log_softmax(pred)
// B=8192, H=2048, D=104.  Outputs: [pred_logsoft (8192*104) | h_t (8192*2048)] f32.
// gemm1 (R4): 128x128 tile, BK=32, 4-buffer LDS (64KB) depth-3 counted-vmcnt
//   pipeline, raw s_barrier (no vmcnt(0) drain), 2 blocks/CU, XOR slot swizzle.
// ---------------------------------------------------------------------------

typedef __bf16 bf16x8 __attribute__((ext_vector_type(8)));
typedef float  f32x4  __attribute__((ext_vector_type(4)));
typedef unsigned short ushort8 __attribute__((ext_vector_type(8)));
typedef float  float4v __attribute__((ext_vector_type(4)));

#define BB 8192
#define HH 2048
#define DD 104

static __device__ __forceinline__ unsigned short f2bf(float f) {
  unsigned u = __float_as_uint(f);
  unsigned r = (u + 0x7FFFu + ((u >> 16) & 1u)) >> 16;  // RNE
  return (unsigned short)r;
}

// async global->LDS, 16B per lane
#define GLD_LDS(g, l)                                                          \
  __builtin_amdgcn_global_load_lds(                                            \
      (__attribute__((address_space(1))) void*)(g),                            \
      (__attribute__((address_space(3))) void*)(l), 16, 0, 0)

#define MEMFENCE asm volatile("" ::: "memory")

// ---------------------------------------------------------------------------
// Conversion kernels (unchanged)
// ---------------------------------------------------------------------------
__global__ __launch_bounds__(256) void conv_bf16_kernel(
    const float* __restrict__ hidden, const float* __restrict__ Uw,
    unsigned short* __restrict__ out_hidden, unsigned short* __restrict__ out_U) {
  long long i = ((long long)blockIdx.x * blockDim.x + threadIdx.x) * 8;
  const float* src; unsigned short* dst; long long off;
  if (i < (long long)BB * HH) { src = hidden; dst = out_hidden; off = i; }
  else { src = Uw; dst = out_U; off = i - (long long)BB * HH; }
  float4v a = *(const float4v*)(src + off);
  float4v b = *(const float4v*)(src + off + 4);
  ushort8 o;
  o[0]=f2bf(a[0]); o[1]=f2bf(a[1]); o[2]=f2bf(a[2]); o[3]=f2bf(a[3]);
  o[4]=f2bf(b[0]); o[5]=f2bf(b[1]); o[6]=f2bf(b[2]); o[7]=f2bf(b[3]);
  *(ushort8*)(dst + off) = o;
}

__global__ __launch_bounds__(256) void pad_bf16_kernel(
    const float* __restrict__ line, const float* __restrict__ Ww,
    const float* __restrict__ Vw,
    unsigned short* __restrict__ line_pad, unsigned short* __restrict__ Ww_pad,
    unsigned short* __restrict__ Vw_pad) {
  int i = blockIdx.x * blockDim.x + threadIdx.x;
  const int N1 = BB * 128;          // 1048576
  const int N2 = N1 + HH * 128;     // +262144
  if (i < N1) {
    int r = i >> 7, c = i & 127;
    line_pad[i] = (c < DD) ? f2bf(line[r * DD + c]) : (unsigned short)0;
  } else if (i < N2) {
    int j = i - N1; int r = j >> 7, c = j & 127;
    Ww_pad[j] = (c < DD) ? f2bf(Ww[r * DD + c]) : (unsigned short)0;
  } else {
    int j = i - N2; int r = j >> 11, c = j & 2047;
    Vw_pad[j] = (r < DD) ? f2bf(Vw[r * 2048 + c]) : (unsigned short)0;
  }
}

// ---------------------------------------------------------------------------
// GEMM1 phase: one K-tile (BK=32). Buffers: A at [buf*4096), B at 16384+[...].
// LDS[row][slotL] = G[row][slotL ^ ((row>>1)&3)]  (slot = 8-elem group).
// Pipeline invariant: entering phase t, in-flight = tiles {t,t+1,t+2} (12);
// issue tile t+3 (16); vmcnt(12) retires exactly tile t; barrier; read; MFMA.
// ---------------------------------------------------------------------------
template <int J>
static __device__ __forceinline__ void ktile1(
    int t, unsigned short* smem,
    const unsigned short* pAh, const unsigned short* pAl,
    const unsigned short* pBu, const unsigned short* pBw,
    unsigned short* dA, unsigned short* dB,
    int arow0, int brow0, int frow, int soff, f32x4 (&acc)[4][4]) {
  constexpr int DST = (J + 3) & 3;
  int ks = t + 3; if (ks > 67) ks = 67;   // tail: dummy re-stage (slot dead)
  const int kb = ks * 32;
  if (kb < 2048) {
    GLD_LDS(pAh + kb, dA + DST * 4096);
    GLD_LDS(pAh + kb + 64 * 2048, dA + DST * 4096 + 2048);
    GLD_LDS(pBu + kb, dB + DST * 4096);
    GLD_LDS(pBu + kb + 64 * 2048, dB + DST * 4096 + 2048);
  } else {
    GLD_LDS(pAl + (kb - 2048), dA + DST * 4096);
    GLD_LDS(pAl + (kb - 2048) + 64 * 128, dA + DST * 4096 + 2048);
    GLD_LDS(pBw + (kb - 2048), dB + DST * 4096);
    GLD_LDS(pBw + (kb - 2048) + 64 * 128, dB + DST * 4096 + 2048);
  }
  asm volatile("s_waitcnt vmcnt(12)" ::: "memory");  // tile t landed (all waves)
  __builtin_amdgcn_s_barrier();
  MEMFENCE;
  const unsigned short* ar = smem + J * 4096;
  const unsigned short* br = smem + 16384 + J * 4096;
  bf16x8 av[4], bv[4];
#pragma unroll
  for (int m = 0; m < 4; ++m)
    av[m] = *(const bf16x8*)(ar + (arow0 + m * 16 + frow) * 32 + soff);
#pragma unroll
  for (int n = 0; n < 4; ++n)
    bv[n] = *(const bf16x8*)(br + (brow0 + n * 16 + frow) * 32 + soff);
  __builtin_amdgcn_s_setprio(1);
#pragma unroll
  for (int m = 0; m < 4; ++m)
#pragma unroll
    for (int n = 0; n < 4; ++n)
      acc[m][n] = __builtin_amdgcn_mfma_f32_16x16x32_bf16(av[m], bv[n], acc[m][n], 0, 0, 0);
  __builtin_amdgcn_s_setprio(0);
  MEMFENCE;                       // pin this phase's LDS reads above barrier #2
  __builtin_amdgcn_s_barrier();   // next phase's GLD may overwrite slot J
  MEMFENCE;
}

__global__ __launch_bounds__(256) void gemm1_kernel(
    const unsigned short* __restrict__ Ahid,   // [8192][2048] bf16
    const unsigned short* __restrict__ Aline,  // [8192][128]  bf16 (zero-pad)
    const unsigned short* __restrict__ BU,     // [2048][2048] bf16
    const unsigned short* __restrict__ BW,     // [2048][128]  bf16 (zero-pad)
    const float* __restrict__ Ub, const float* __restrict__ Wb,
    float* __restrict__ outH, unsigned short* __restrict__ outHbf) {
  __shared__ unsigned short smem[32768];   // 64 KB: A 4x[128][32] | B 4x[128][32]
  const int t = threadIdx.x;
  const int l = t & 63;
  const int wid = t >> 6, wr = wid >> 1, wc = wid & 1;

  // XCD-chunked bijective swizzle: 1024 wgs, 8 XCDs, 128/chunk
  const int bid = blockIdx.x;
  const int wg = (bid & 7) * 128 + (bid >> 3);
  const int brow = (wg >> 4) * 128;   // 64 M tiles
  const int bcol = (wg & 15) * 128;   // 16 N tiles

  const int frow = l & 15, lhi = l >> 4;
  const int soff = ((lhi ^ ((frow >> 1) & 3)) * 8);   // swizzled read slot

  // staging: thread t -> row t>>2 (64B rows), source slot pre-swizzled
  const int srow = t >> 2;
  const int sslot = (((t & 3) ^ ((srow >> 1) & 3)) * 8);
  const unsigned short* pAh = Ahid + (size_t)(brow + srow) * 2048 + sslot;
  const unsigned short* pAl = Aline + (size_t)(brow + srow) * 128 + sslot;
  const unsigned short* pBu = BU + (size_t)(bcol + srow) * 2048 + sslot;
  const unsigned short* pBw = BW + (size_t)(bcol + srow) * 128 + sslot;
  unsigned short* dA = smem + t * 8;            // + buf*4096 (+2048 rows 64-127)
  unsigned short* dB = smem + 16384 + t * 8;

  const int arow0 = wr * 64, brow0 = wc * 64;

  f32x4 acc[4][4] = {};

  // prologue: stage tiles 0,1,2 into bufs 0,1,2 (12 loads in flight)
#pragma unroll
  for (int p = 0; p < 3; ++p) {
    GLD_LDS(pAh + p * 32, dA + p * 4096);
    GLD_LDS(pAh + p * 32 + 64 * 2048, dA + p * 4096 + 2048);
    GLD_LDS(pBu + p * 32, dB + p * 4096);
    GLD_LDS(pBu + p * 32 + 64 * 2048, dB + p * 4096 + 2048);
  }

  // 68 K-tiles of 32 (K = 2048 hidden/U_w + 128 line/W_w), 17 x 4
  for (int it = 0; it < 17; ++it) {
    const int t4 = it * 4;
    ktile1<0>(t4 + 0, smem, pAh, pAl, pBu, pBw, dA, dB, arow0, brow0, frow, soff, acc);
    ktile1<1>(t4 + 1, smem, pAh, pAl, pBu, pBw, dA, dB, arow0, brow0, frow, soff, acc);
    ktile1<2>(t4 + 2, smem, pAh, pAl, pBu, pBw, dA, dB, arow0, brow0, frow, soff, acc);
    ktile1<3>(t4 + 3, smem, pAh, pAl, pBu, pBw, dA, dB, arow0, brow0, frow, soff, acc);
  }

  // epilogue: +bias, sigmoid, dual write (C/D layout: col=l&15, row=(l>>4)*4+j)
#pragma unroll
  for (int n = 0; n < 4; ++n) {
    const int col = bcol + wc * 64 + n * 16 + frow;
    const float bias = Ub[col] + Wb[col];
#pragma unroll
    for (int m = 0; m < 4; ++m) {
      const int r0 = brow + wr * 64 + m * 16 + lhi * 4;
#pragma unroll
      for (int jj = 0; jj < 4; ++jj) {
        const float v = acc[m][n][jj] + bias;
        const float h = 1.0f / (1.0f + __expf(-v));
        const size_t idx = (size_t)(r0 + jj) * HH + col;
        outH[idx] = h;
        outHbf[idx] = f2bf(h);
      }
    }
  }
}

// ---------------------------------------------------------------------------
// GEMM2 (unchanged): pred = h_t@V_w.T + V_b + fused seg log-softmax
// ---------------------------------------------------------------------------
template <int NM, int NN>
static __device__ __forceinline__ void mfma_step(
    const unsigned short* sA, const unsigned short* sB, int arow0, int brow0,
    int frow, int fk, f32x4 (&acc)[NM][NN]) {
  bf16x8 af[NM], bfr[NN];
#pragma unroll
  for (int m = 0; m < NM; ++m)
    af[m] = *(const bf16x8*)(sA + (arow0 + m * 16 + frow) * 32 + fk);
#pragma unroll
  for (int n = 0; n < NN; ++n)
    bfr[n] = *(const bf16x8*)(sB + (brow0 + n * 16 + frow) * 32 + fk);
#pragma unroll
  for (int m = 0; m < NM; ++m)
#pragma unroll
    for (int n = 0; n < NN; ++n)
      acc[m][n] = __builtin_amdgcn_mfma_f32_16x16x32_bf16(af[m], bfr[n], acc[m][n], 0, 0, 0);
}

__global__ __launch_bounds__(256, 2) void gemm2_kernel(
    const unsigned short* __restrict__ A,   // h_t bf16 [8192][2048]
    const unsigned short* __restrict__ Bm,  // Vw_pad [128][2048]
    const float* __restrict__ Vb,
    float* __restrict__ outLS) {            // [8192][104] f32
  __shared__ unsigned short sA[64 * 32];
  __shared__ unsigned short sB[128 * 32];
  __shared__ float pred[64 * 105];
  const int t = threadIdx.x;
  const int l = t & 63;
  const int wid = t >> 6, wr = wid >> 1, wc = wid & 1;
  const int brow = blockIdx.x * 64;
  const int srow = t >> 2, scg = t & 3;
  const int frow = l & 15, fk = (l >> 4) * 8;

  const unsigned short* gA = A + (size_t)(brow + srow) * HH + scg * 8;
  const unsigned short* gB = Bm + (size_t)srow * HH + scg * 8;
  unsigned short* lA = sA + t * 8;
  unsigned short* lB = sB + t * 8;

  f32x4 acc[2][4] = {};
  for (int ks = 0; ks < 64; ++ks) {
    __syncthreads();
    GLD_LDS(gA, lA);
    GLD_LDS(gB, lB);
    GLD_LDS(gB + 64 * HH, lB + 64 * 32);
    gA += 32; gB += 32;
    __syncthreads();
    mfma_step<2, 4>(sA, sB, wr * 32, wc * 64, frow, fk, acc);
  }

#pragma unroll
  for (int n = 0; n < 4; ++n) {
    const int col = wc * 64 + n * 16 + frow;
    if (col < DD) {
      const float vb = Vb[col];
#pragma unroll
      for (int m = 0; m < 2; ++m) {
        const int r0 = wr * 32 + m * 16 + (l >> 4) * 4;
#pragma unroll
        for (int j = 0; j < 4; ++j)
          pred[(r0 + j) * 105 + col] = acc[m][n][j] + vb;
      }
    }
  }
  __syncthreads();

  if (t < 64) {
    const int segb[11] = {0, 13, 26, 39, 48, 52, 65, 78, 91, 100, 104};
    const float* p = pred + t * 105;
    float* o = outLS + (size_t)(brow + t) * DD;
    for (int s = 0; s < 10; ++s) {
      const int a = segb[s], b = segb[s + 1];
      float mx = -3.0e38f;
      for (int c = a; c < b; ++c) mx = fmaxf(mx, p[c]);
      float sum = 0.0f;
      for (int c = a; c < b; ++c) sum += __expf(p[c] - mx);
      const float ls = __logf(sum) + mx;
      for (int c = a; c < b; ++c) o[c] = p[c] - ls;
    }
  }
}

// ---------------------------------------------------------------------------
// Launch
// ---------------------------------------------------------------------------
extern "C" void kernel_launch(void* const* d_in, const int* in_sizes, int n_in,
                              void* d_out, int out_size, void* d_ws, size_t ws_size,
                              hipStream_t stream) {
  (void)in_sizes; (void)n_in; (void)out_size; (void)ws_size;
  const float* line   = (const float*)d_in[0];
  const float* hidden = (const float*)d_in[1];
  const float* Uw     = (const float*)d_in[2];
  const float* Ub     = (const float*)d_in[3];
  const float* Ww     = (const float*)d_in[4];
  const float* Wb     = (const float*)d_in[5];
  const float* Vw     = (const float*)d_in[6];
  const float* Vb     = (const float*)d_in[7];

  char* ws = (char*)d_ws;
  unsigned short* hid_bf  = (unsigned short*)(ws);              // 33,554,432 B
  unsigned short* U_bf    = (unsigned short*)(ws + 33554432);   //  8,388,608
  unsigned short* line_bf = (unsigned short*)(ws + 41943040);   //  2,097,152
  unsigned short* Ww_bf   = (unsigned short*)(ws + 44040192);   //    524,288
  unsigned short* Vw_bf   = (unsigned short*)(ws + 44564480);   //    524,288
  unsigned short* ht_bf   = (unsigned short*)(ws + 45088768);   // 33,554,432

  float* outLS = (float*)d_out;                    // [8192][104]
  float* outH  = (float*)d_out + (size_t)BB * DD;  // [8192][2048]

  conv_bf16_kernel<<<10240, 256, 0, stream>>>(hidden, Uw, hid_bf, U_bf);
  pad_bf16_kernel<<<6144, 256, 0, stream>>>(line, Ww, Vw, line_bf, Ww_bf, Vw_bf);
  gemm1_kernel<<<1024, 256, 0, stream>>>(hid_bf, line_bf, U_bf, Ww_bf, Ub, Wb,
                                         outH, ht_bf);
  gemm2_kernel<<<128, 256, 0, stream>>>(ht_bf, Vw_bf, Vb, outLS);
}

// Round 5
// 134.851 us; speedup vs baseline: 1.1842x; 1.1721x over previous
//
#include <hip/hip_runtime.h>
#include <cstdint>
#include <cstddef>

// ---------------------------------------------------------------------------
// RNN_No_FFNN: h_t = sigmoid(hidden@U_w.T + U_b + line@W_w.T + W_b)
//              pred = h_t@V_w.T + V_b ; out0 = segmented log_softmax(pred)
// B=8192, H=2048, D=104.  Outputs: [pred_logsoft (8192*104) | h_t (8192*2048)] f32.
// gemm1 (R5): 256x256 tile, 512 thr (2x4 waves, 128x64/wave), BK=64,
//   2 full-tile LDS dbufs (128KB), 4 phases/K-tile m201-style interleave,
//   counted vmcnt(4) twice per K-tile (never 0 in main loop), 1 barrier/phase,
//   XOR slot swizzle (R4-proven conflict-free), grid 256 = 1 block/CU.
// ---------------------------------------------------------------------------

typedef __bf16 bf16x8 __attribute__((ext_vector_type(8)));
typedef float  f32x4  __attribute__((ext_vector_type(4)));
typedef unsigned short ushort8 __attribute__((ext_vector_type(8)));
typedef float  float4v __attribute__((ext_vector_type(4)));

#define BB 8192
#define HH 2048
#define DD 104

static __device__ __forceinline__ unsigned short f2bf(float f) {
  unsigned u = __float_as_uint(f);
  unsigned r = (u + 0x7FFFu + ((u >> 16) & 1u)) >> 16;  // RNE
  return (unsigned short)r;
}

#define GLD_LDS(g, l)                                                          \
  __builtin_amdgcn_global_load_lds(                                            \
      (__attribute__((address_space(1))) void*)(g),                            \
      (__attribute__((address_space(3))) void*)(l), 16, 0, 0)

#define MEMFENCE asm volatile("" ::: "memory")
#define MFMA16(a, b, c) __builtin_amdgcn_mfma_f32_16x16x32_bf16((a), (b), (c), 0, 0, 0)

// ---------------------------------------------------------------------------
// Conversion kernels (unchanged)
// ---------------------------------------------------------------------------
__global__ __launch_bounds__(256) void conv_bf16_kernel(
    const float* __restrict__ hidden, const float* __restrict__ Uw,
    unsigned short* __restrict__ out_hidden, unsigned short* __restrict__ out_U) {
  long long i = ((long long)blockIdx.x * blockDim.x + threadIdx.x) * 8;
  const float* src; unsigned short* dst; long long off;
  if (i < (long long)BB * HH) { src = hidden; dst = out_hidden; off = i; }
  else { src = Uw; dst = out_U; off = i - (long long)BB * HH; }
  float4v a = *(const float4v*)(src + off);
  float4v b = *(const float4v*)(src + off + 4);
  ushort8 o;
  o[0]=f2bf(a[0]); o[1]=f2bf(a[1]); o[2]=f2bf(a[2]); o[3]=f2bf(a[3]);
  o[4]=f2bf(b[0]); o[5]=f2bf(b[1]); o[6]=f2bf(b[2]); o[7]=f2bf(b[3]);
  *(ushort8*)(dst + off) = o;
}

__global__ __launch_bounds__(256) void pad_bf16_kernel(
    const float* __restrict__ line, const float* __restrict__ Ww,
    const float* __restrict__ Vw,
    unsigned short* __restrict__ line_pad, unsigned short* __restrict__ Ww_pad,
    unsigned short* __restrict__ Vw_pad) {
  int i = blockIdx.x * blockDim.x + threadIdx.x;
  const int N1 = BB * 128;          // 1048576
  const int N2 = N1 + HH * 128;     // +262144
  if (i < N1) {
    int r = i >> 7, c = i & 127;
    line_pad[i] = (c < DD) ? f2bf(line[r * DD + c]) : (unsigned short)0;
  } else if (i < N2) {
    int j = i - N1; int r = j >> 7, c = j & 127;
    Ww_pad[j] = (c < DD) ? f2bf(Ww[r * DD + c]) : (unsigned short)0;
  } else {
    int j = i - N2; int r = j >> 11, c = j & 2047;
    Vw_pad[j] = (r < DD) ? f2bf(Vw[r * 2048 + c]) : (unsigned short)0;
  }
}

// ---------------------------------------------------------------------------
// GEMM1 K-tile: 4 phases. LDS layout (ushort): A bufs [0,32768), B [32768,65536);
// per buf 16384 = [kh:2][row:256][slot:4 x 8elem], slot XOR-swizzled by row:
// LDS[kh][row][s] = G[row][kb + kh*32 + (s ^ ((row>>1)&3))*8 ..+8].
// Phase p stages one quarter (2 GLD/thread) of tile t+1 into buf^1:
//   p1: A-kh0', p2: B-kh0', p3: A-kh1', p4: B-kh1'.
// vmcnt(4) before barriers of p2/p4: certifies quarters staged 3-4 phases ago.
// Safety (1 barrier/phase): GLD at phase q overwrites a region last ds_read at
// q-4; those reads complete before their own MFMA (data dep) which precedes
// their phase-end barrier -> 4 barriers separate read from overwrite.
// ---------------------------------------------------------------------------
template <int BUF, bool STAGE, bool TAIL>
static __device__ __forceinline__ void ktile(
    int kb_n,  // k-base of tile t+1 (if STAGE)
    unsigned short* smem,
    const unsigned short* pAh, const unsigned short* pAl,
    const unsigned short* pBu, const unsigned short* pBw,
    unsigned short* dA, unsigned short* dB,
    int aoffs, int boffs, f32x4 (&acc)[8][4]) {
  constexpr int SB = BUF ^ 1;
  const unsigned short* Ab = smem + BUF * 16384;
  const unsigned short* Bb = smem + 32768 + BUF * 16384;
  const bool hi = STAGE && (kb_n >= 2048);
  const unsigned short* sA0 = hi ? pAl + (kb_n - 2048) : pAh + kb_n;
  const unsigned short* sB0 = hi ? pBw + (kb_n - 2048) : pBu + kb_n;
  const int rstr = hi ? 128 : 2048;     // +128 rows for the j=1 load
  bf16x8 a[8], b0, b1;

  // ---- phase 1: kh=0, nh=0 ----
#pragma unroll
  for (int mi = 0; mi < 8; ++mi) a[mi] = *(const bf16x8*)(Ab + aoffs + mi * 512);
  b0 = *(const bf16x8*)(Bb + boffs);
  b1 = *(const bf16x8*)(Bb + boffs + 512);
  if (STAGE) {
    GLD_LDS(sA0, dA + SB * 16384);
    GLD_LDS(sA0 + 128 * rstr, dA + SB * 16384 + 4096);
  }
  __builtin_amdgcn_s_setprio(1);
#pragma unroll
  for (int mi = 0; mi < 8; ++mi) {
    acc[mi][0] = MFMA16(a[mi], b0, acc[mi][0]);
    acc[mi][1] = MFMA16(a[mi], b1, acc[mi][1]);
  }
  __builtin_amdgcn_s_setprio(0);
  MEMFENCE; __builtin_amdgcn_s_barrier(); MEMFENCE;

  // ---- phase 2: kh=0, nh=1 (reuse a[]) ----
  b0 = *(const bf16x8*)(Bb + boffs + 1024);
  b1 = *(const bf16x8*)(Bb + boffs + 1536);
  if (STAGE) {
    GLD_LDS(sB0, dB + SB * 16384);
    GLD_LDS(sB0 + 128 * rstr, dB + SB * 16384 + 4096);
  }
  __builtin_amdgcn_s_setprio(1);
#pragma unroll
  for (int mi = 0; mi < 8; ++mi) {
    acc[mi][2] = MFMA16(a[mi], b0, acc[mi][2]);
    acc[mi][3] = MFMA16(a[mi], b1, acc[mi][3]);
  }
  __builtin_amdgcn_s_setprio(0);
  if (TAIL) { asm volatile("s_waitcnt vmcnt(0)" ::: "memory"); }
  else      { asm volatile("s_waitcnt vmcnt(4)" ::: "memory"); }
  MEMFENCE; __builtin_amdgcn_s_barrier(); MEMFENCE;

  // ---- phase 3: kh=1, nh=0 ----
#pragma unroll
  for (int mi = 0; mi < 8; ++mi) a[mi] = *(const bf16x8*)(Ab + 8192 + aoffs + mi * 512);
  b0 = *(const bf16x8*)(Bb + 8192 + boffs);
  b1 = *(const bf16x8*)(Bb + 8192 + boffs + 512);
  if (STAGE) {
    GLD_LDS(sA0 + 32, dA + SB * 16384 + 8192);
    GLD_LDS(sA0 + 32 + 128 * rstr, dA + SB * 16384 + 8192 + 4096);
  }
  __builtin_amdgcn_s_setprio(1);
#pragma unroll
  for (int mi = 0; mi < 8; ++mi) {
    acc[mi][0] = MFMA16(a[mi], b0, acc[mi][0]);
    acc[mi][1] = MFMA16(a[mi], b1, acc[mi][1]);
  }
  __builtin_amdgcn_s_setprio(0);
  MEMFENCE; __builtin_amdgcn_s_barrier(); MEMFENCE;

  // ---- phase 4: kh=1, nh=1 (reuse a[]) ----
  b0 = *(const bf16x8*)(Bb + 8192 + boffs + 1024);
  b1 = *(const bf16x8*)(Bb + 8192 + boffs + 1536);
  if (STAGE) {
    GLD_LDS(sB0 + 32, dB + SB * 16384 + 8192);
    GLD_LDS(sB0 + 32 + 128 * rstr, dB + SB * 16384 + 8192 + 4096);
  }
  __builtin_amdgcn_s_setprio(1);
#pragma unroll
  for (int mi = 0; mi < 8; ++mi) {
    acc[mi][2] = MFMA16(a[mi], b0, acc[mi][2]);
    acc[mi][3] = MFMA16(a[mi], b1, acc[mi][3]);
  }
  __builtin_amdgcn_s_setprio(0);
  if (!TAIL) { asm volatile("s_waitcnt vmcnt(4)" ::: "memory"); }
  MEMFENCE; __builtin_amdgcn_s_barrier(); MEMFENCE;
}

__global__ __launch_bounds__(512, 2) void gemm1_kernel(
    const unsigned short* __restrict__ Ahid,   // [8192][2048] bf16
    const unsigned short* __restrict__ Aline,  // [8192][128]  bf16 (zero-pad)
    const unsigned short* __restrict__ BU,     // [2048][2048] bf16
    const unsigned short* __restrict__ BW,     // [2048][128]  bf16 (zero-pad)
    const float* __restrict__ Ub, const float* __restrict__ Wb,
    float* __restrict__ outH, unsigned short* __restrict__ outHbf) {
  __shared__ unsigned short smem[65536];   // 128 KB
  const int t = threadIdx.x;
  const int l = t & 63;
  const int wid = t >> 6;
  const int wr = wid >> 2, wc = wid & 3;   // 2 x 4 waves, 128x64 out each

  // bijective XCD-chunked swizzle: 256 wgs, 8 XCDs, 32/chunk
  const int bid = blockIdx.x;
  const int wg = (bid & 7) * 32 + (bid >> 3);
  const int brow = (wg >> 3) * 256;   // 32 M tiles
  const int bcol = (wg & 7) * 256;    // 8 N tiles

  const int frow = l & 15, lhi = l >> 4;
  const int slot8 = (lhi ^ ((frow >> 1) & 3)) * 8;   // swizzled read slot

  // staging: thread t -> rows t>>2 and t>>2+128; source col pre-swizzled
  const int srow = t >> 2;
  const int scol = (((t & 3) ^ ((t >> 3) & 3)) * 8);
  const unsigned short* pAh = Ahid + (size_t)(brow + srow) * 2048 + scol;
  const unsigned short* pAl = Aline + (size_t)(brow + srow) * 128 + scol;
  const unsigned short* pBu = BU + (size_t)(bcol + srow) * 2048 + scol;
  const unsigned short* pBw = BW + (size_t)(bcol + srow) * 128 + scol;
  unsigned short* dA = smem + t * 8;           // + SB*16384 + kh*8192 + j*4096
  unsigned short* dB = smem + 32768 + t * 8;

  const int aoffs = (wr * 128 + frow) * 32 + slot8;   // + kh*8192 + mi*512
  const int boffs = (wc * 64 + frow) * 32 + slot8;    // + kh*8192 + nh*1024 + nj*512

  f32x4 acc[8][4] = {};

  // prologue: stage tile 0 into buf0: A-k0, B-k0 first, then A-k1, B-k1
  GLD_LDS(pAh, dA);
  GLD_LDS(pAh + 128 * 2048, dA + 4096);
  GLD_LDS(pBu, dB);
  GLD_LDS(pBu + 128 * 2048, dB + 4096);
  GLD_LDS(pAh + 32, dA + 8192);
  GLD_LDS(pAh + 32 + 128 * 2048, dA + 8192 + 4096);
  GLD_LDS(pBu + 32, dB + 8192);
  GLD_LDS(pBu + 32 + 128 * 2048, dB + 8192 + 4096);
  asm volatile("s_waitcnt vmcnt(4)" ::: "memory");   // A-k0, B-k0 landed
  __builtin_amdgcn_s_barrier(); MEMFENCE;

  // K = 2176 = 34 tiles of 64 (2048 hidden/U_w + 128 line/W_w concat)
  // tiles 0..31 (16 pairs), each stages tile t+1
  for (int it = 0; it < 16; ++it) {
    ktile<0, true, false>((2 * it + 1) * 64, smem, pAh, pAl, pBu, pBw, dA, dB, aoffs, boffs, acc);
    ktile<1, true, false>((2 * it + 2) * 64, smem, pAh, pAl, pBu, pBw, dA, dB, aoffs, boffs, acc);
  }
  // tile 32 stages tile 33 (kb = 2112); tile 33 peeled, no staging
  ktile<0, true, false>(33 * 64, smem, pAh, pAl, pBu, pBw, dA, dB, aoffs, boffs, acc);
  ktile<1, false, true>(0, smem, pAh, pAl, pBu, pBw, dA, dB, aoffs, boffs, acc);

  // epilogue: +bias, sigmoid, dual write (C/D: col = frow, row = lhi*4 + jj)
#pragma unroll
  for (int nf = 0; nf < 4; ++nf) {
    const int col = bcol + wc * 64 + nf * 16 + frow;
    const float bias = Ub[col] + Wb[col];
#pragma unroll
    for (int mi = 0; mi < 8; ++mi) {
      const int r0 = brow + wr * 128 + mi * 16 + lhi * 4;
#pragma unroll
      for (int jj = 0; jj < 4; ++jj) {
        const float v = acc[mi][nf][jj] + bias;
        const float h = 1.0f / (1.0f + __expf(-v));
        const size_t idx = (size_t)(r0 + jj) * HH + col;
        outH[idx] = h;
        outHbf[idx] = f2bf(h);
      }
    }
  }
}

// ---------------------------------------------------------------------------
// GEMM2 (unchanged): pred = h_t@V_w.T + V_b + fused seg log-softmax
// ---------------------------------------------------------------------------
template <int NM, int NN>
static __device__ __forceinline__ void mfma_step(
    const unsigned short* sA, const unsigned short* sB, int arow0, int brow0,
    int frow, int fk, f32x4 (&acc)[NM][NN]) {
  bf16x8 af[NM], bfr[NN];
#pragma unroll
  for (int m = 0; m < NM; ++m)
    af[m] = *(const bf16x8*)(sA + (arow0 + m * 16 + frow) * 32 + fk);
#pragma unroll
  for (int n = 0; n < NN; ++n)
    bfr[n] = *(const bf16x8*)(sB + (brow0 + n * 16 + frow) * 32 + fk);
#pragma unroll
  for (int m = 0; m < NM; ++m)
#pragma unroll
    for (int n = 0; n < NN; ++n)
      acc[m][n] = MFMA16(af[m], bfr[n], acc[m][n]);
}

__global__ __launch_bounds__(256, 2) void gemm2_kernel(
    const unsigned short* __restrict__ A,   // h_t bf16 [8192][2048]
    const unsigned short* __restrict__ Bm,  // Vw_pad [128][2048]
    const float* __restrict__ Vb,
    float* __restrict__ outLS) {            // [8192][104] f32
  __shared__ unsigned short sA[64 * 32];
  __shared__ unsigned short sB[128 * 32];
  __shared__ float pred[64 * 105];
  const int t = threadIdx.x;
  const int l = t & 63;
  const int wid = t >> 6, wr = wid >> 1, wc = wid & 1;
  const int brow = blockIdx.x * 64;
  const int srow = t >> 2, scg = t & 3;
  const int frow = l & 15, fk = (l >> 4) * 8;

  const unsigned short* gA = A + (size_t)(brow + srow) * HH + scg * 8;
  const unsigned short* gB = Bm + (size_t)srow * HH + scg * 8;
  unsigned short* lA = sA + t * 8;
  unsigned short* lB = sB + t * 8;

  f32x4 acc[2][4] = {};
  for (int ks = 0; ks < 64; ++ks) {
    __syncthreads();
    GLD_LDS(gA, lA);
    GLD_LDS(gB, lB);
    GLD_LDS(gB + 64 * HH, lB + 64 * 32);
    gA += 32; gB += 32;
    __syncthreads();
    mfma_step<2, 4>(sA, sB, wr * 32, wc * 64, frow, fk, acc);
  }

#pragma unroll
  for (int n = 0; n < 4; ++n) {
    const int col = wc * 64 + n * 16 + frow;
    if (col < DD) {
      const float vb = Vb[col];
#pragma unroll
      for (int m = 0; m < 2; ++m) {
        const int r0 = wr * 32 + m * 16 + (l >> 4) * 4;
#pragma unroll
        for (int j = 0; j < 4; ++j)
          pred[(r0 + j) * 105 + col] = acc[m][n][j] + vb;
      }
    }
  }
  __syncthreads();

  if (t < 64) {
    const int segb[11] = {0, 13, 26, 39, 48, 52, 65, 78, 91, 100, 104};
    const float* p = pred + t * 105;
    float* o = outLS + (size_t)(brow + t) * DD;
    for (int s = 0; s < 10; ++s) {
      const int a = segb[s], b = segb[s + 1];
      float mx = -3.0e38f;
      for (int c = a; c < b; ++c) mx = fmaxf(mx, p[c]);
      float sum = 0.0f;
      for (int c = a; c < b; ++c) sum += __expf(p[c] - mx);
      const float ls = __logf(sum) + mx;
      for (int c = a; c < b; ++c) o[c] = p[c] - ls;
    }
  }
}

// ---------------------------------------------------------------------------
// Launch
// ---------------------------------------------------------------------------
extern "C" void kernel_launch(void* const* d_in, const int* in_sizes, int n_in,
                              void* d_out, int out_size, void* d_ws, size_t ws_size,
                              hipStream_t stream) {
  (void)in_sizes; (void)n_in; (void)out_size; (void)ws_size;
  const float* line   = (const float*)d_in[0];
  const float* hidden = (const float*)d_in[1];
  const float* Uw     = (const float*)d_in[2];
  const float* Ub     = (const float*)d_in[3];
  const float* Ww     = (const float*)d_in[4];
  const float* Wb     = (const float*)d_in[5];
  const float* Vw     = (const float*)d_in[6];
  const float* Vb     = (const float*)d_in[7];

  char* ws = (char*)d_ws;
  unsigned short* hid_bf  = (unsigned short*)(ws);              // 33,554,432 B
  unsigned short* U_bf    = (unsigned short*)(ws + 33554432);   //  8,388,608
  unsigned short* line_bf = (unsigned short*)(ws + 41943040);   //  2,097,152
  unsigned short* Ww_bf   = (unsigned short*)(ws + 44040192);   //    524,288
  unsigned short* Vw_bf   = (unsigned short*)(ws + 44564480);   //    524,288
  unsigned short* ht_bf   = (unsigned short*)(ws + 45088768);   // 33,554,432

  float* outLS = (float*)d_out;                    // [8192][104]
  float* outH  = (float*)d_out + (size_t)BB * DD;  // [8192][2048]

  conv_bf16_kernel<<<10240, 256, 0, stream>>>(hidden, Uw, hid_bf, U_bf);
  pad_bf16_kernel<<<6144, 256, 0, stream>>>(line, Ww, Vw, line_bf, Ww_bf, Vw_bf);
  gemm1_kernel<<<256, 512, 0, stream>>>(hid_bf, line_bf, U_bf, Ww_bf, Ub, Wb,
                                        outH, ht_bf);
  gemm2_kernel<<<128, 256, 0, stream>>>(ht_bf, Vw_bf, Vb, outLS);
}